// Round 6
// baseline (250.895 us; speedup 1.0000x reference)
//
#include <hip/hip_runtime.h>

// UCBNorm fully fused: ONE kernel + one 8-byte memset (counter init).
// Manual grid barrier via device-scope atomics (hipLaunchCooperativeKernel is
// broken in this harness - round 3). Co-residency guaranteed: 512 blocks,
// __launch_bounds__(256) => VGPR<=256 => worst case exactly 2 blocks/CU ->
// all 512 resident (LDS 17.3KB/block, 4x margin on waves/LDS).
//
// Math (softmax(prior) over size-1 axis == 1 -> constant 1/sqrt(1+EPS)):
//   p_k = exp(qa_k x^2 + qb_k x + qc_k)   (expanded -0.5(x-m)^2/(sp(v)+EPS))
//   den = EPS + sum_k p,  tau = p/den,  S[k,d] = EPS + sum_{b,t} tau
//   e = (sum_t tau x)/(T S),  var = (sum_t tau^3 x^2)/(T S^3)
//   out = (1/sqrt(1+EPS)) * rden * (x * sum_k p r_k  -  sum_k p e_k r_k)
//
// Phase1: block=(b,tc) 256thr=d, 16 t serial; x staged to LDS; partials to ws.
// Barrier. Phase2 (blocks 0..127): reduce partials -> er[B][K][2][D].
// Barrier. Phase3: recompute p from LDS x, write out. x reads HBM once.

namespace {
constexpr int K = 8, B = 16, T = 512, D = 256;
constexpr float EPS = 1e-3f;
constexpr int TC   = 32;             // t-chunks
constexpr int TL   = T / TC;         // 16 t per block
constexpr int NBLK = B * TC;         // 512 blocks
constexpr int PSZ  = K * B * TC * D; // 1048576 floats per partial array
constexpr int ERSZ = B * K * 2 * D;  // 65536 floats
}

__device__ __forceinline__ void grid_barrier(unsigned* ctr, unsigned nblk) {
  __syncthreads();
  if (threadIdx.x == 0) {
    __threadfence();
    __hip_atomic_fetch_add(ctr, 1u, __ATOMIC_ACQ_REL, __HIP_MEMORY_SCOPE_AGENT);
    while (__hip_atomic_load(ctr, __ATOMIC_ACQUIRE, __HIP_MEMORY_SCOPE_AGENT) < nblk)
      __builtin_amdgcn_s_sleep(2);
    __threadfence();
  }
  __syncthreads();
}

__global__ __launch_bounds__(256) void ucb_all(
    const float* __restrict__ x, const float* __restrict__ mean,
    const float* __restrict__ variance,
    float* __restrict__ pt, float* __restrict__ p1s, float* __restrict__ p3s,
    float* __restrict__ er, unsigned* __restrict__ ctr,
    float* __restrict__ out)
{
  __shared__ float xl[TL][D];      // 16 KB x cache (persists across phases)
  __shared__ float reds[B][17];    // 1.1 KB fin reduce

  const int tid = threadIdx.x;
  const int d   = tid;
  const int b   = blockIdx.x >> 5;
  const int tc  = blockIdx.x & 31;

  // ---- per-(k,d) quadratic coefficients ----
  float qa[K], qb[K], qc[K];
#pragma unroll
  for (int k = 0; k < K; ++k) {
    float mk = mean[k*D + d];
    float sp = log1pf(__expf(variance[k*D + d]));   // softplus
    float nh = -0.5f / (sp + EPS);
    qa[k] = nh;
    qb[k] = -2.0f * nh * mk;
    qc[k] = nh * mk * mk;
  }

  // ---------------- phase 1: partial sums over this block's 16 t ----------
  float ast[K], as1[K], as3[K];
#pragma unroll
  for (int k = 0; k < K; ++k) { ast[k]=0.f; as1[k]=0.f; as3[k]=0.f; }

  const float* xp = x + ((size_t)b*T + (size_t)tc*TL)*D + d;
#pragma unroll 4
  for (int t = 0; t < TL; ++t) {
    float xv = xp[(size_t)t*D];
    xl[t][d] = xv;
    float x2 = xv*xv;
    float p[K];
#pragma unroll
    for (int k = 0; k < K; ++k)
      p[k] = __expf(fmaf(qa[k], x2, fmaf(qb[k], xv, qc[k])));
    float den = EPS + ((p[0]+p[1])+(p[2]+p[3])) + ((p[4]+p[5])+(p[6]+p[7]));
    float rden = __builtin_amdgcn_rcpf(den);
#pragma unroll
    for (int k = 0; k < K; ++k) {
      float tau = p[k]*rden;
      float tx  = tau*xv;
      ast[k] += tau;
      as1[k] += tx;
      as3[k]  = fmaf(tx*tx, tau, as3[k]);   // tau^3 x^2
    }
  }

#pragma unroll
  for (int k = 0; k < K; ++k) {             // [K][B][TC][D], coalesced
    const size_t idx = ((size_t)((k*B + b)*TC + tc))*D + d;
    pt[idx] = ast[k]; p1s[idx] = as1[k]; p3s[idx] = as3[k];
  }

  grid_barrier(ctr + 0, NBLK);

  // ---------------- phase 2: finalize er (blocks 0..127) ------------------
  if (blockIdx.x < 128) {
    const int k  = blockIdx.x >> 4;
    const int d0 = (blockIdx.x & 15) * 16;
    const int dl = tid & 15;
    const int bb = tid >> 4;
    float a0 = 0.f, a1 = 0.f, a3 = 0.f;
    const size_t base = ((size_t)(k*B + bb)*TC)*D + d0 + dl;
#pragma unroll
    for (int t2 = 0; t2 < TC; ++t2) {
      a0 += pt [base + (size_t)t2*D];
      a1 += p1s[base + (size_t)t2*D];
      a3 += p3s[base + (size_t)t2*D];
    }
    reds[bb][dl] = a0;
    __syncthreads();
    if (tid < 16) {                          // cross-b sum -> rS
      float s = 0.f;
#pragma unroll
      for (int b2 = 0; b2 < B; ++b2) s += reds[b2][tid];
      reds[0][tid] = 1.0f / (s + EPS);
    }
    __syncthreads();
    const float rS = reds[0][dl];
    const float rT = 1.0f / T;
    const float e  = a1 * rT * rS;
    const float vv = a3 * rT * (rS*rS*rS);
    const float r  = rsqrtf(vv + EPS);
    er[((size_t)(bb*K + k)*2 + 0)*D + d0 + dl] = e;   // [B][K][2][D]
    er[((size_t)(bb*K + k)*2 + 1)*D + d0 + dl] = r;
  }

  grid_barrier(ctr + 1, NBLK);

  // ---------------- phase 3: output (x from LDS) --------------------------
  float rr[K], erc[K];
#pragma unroll
  for (int k = 0; k < K; ++k) {              // coalesced 1KB loads
    float e = er[((size_t)(b*K + k)*2 + 0)*D + d];
    float r = er[((size_t)(b*K + k)*2 + 1)*D + d];
    rr[k] = r; erc[k] = e*r;
  }

  const float isp = 0.99950037f;             // 1/sqrt(1+EPS)
  float* op = out + ((size_t)b*T + (size_t)tc*TL)*D + d;
#pragma unroll 4
  for (int t = 0; t < TL; ++t) {
    float xv = xl[t][d];
    float x2 = xv*xv;
    float p[K];
#pragma unroll
    for (int k = 0; k < K; ++k)
      p[k] = __expf(fmaf(qa[k], x2, fmaf(qb[k], xv, qc[k])));
    float den = EPS + ((p[0]+p[1])+(p[2]+p[3])) + ((p[4]+p[5])+(p[6]+p[7]));
    float rden = __builtin_amdgcn_rcpf(den);
    float acc1 = 0.f, acc2 = 0.f;
#pragma unroll
    for (int k = 0; k < K; ++k) {
      acc1 = fmaf(p[k], rr[k],  acc1);       // sum p*r
      acc2 = fmaf(p[k], erc[k], acc2);       // sum p*e*r
    }
    op[(size_t)t*D] = (xv*acc1 - acc2) * rden * isp;
  }
}

extern "C" void kernel_launch(void* const* d_in, const int* in_sizes, int n_in,
                              void* d_out, int out_size, void* d_ws, size_t ws_size,
                              hipStream_t stream) {
  const float* x        = (const float*)d_in[0];
  const float* mean     = (const float*)d_in[1];
  const float* variance = (const float*)d_in[2];
  // d_in[3] (prior): softmax over size-1 axis == 1 -> constant baked in.

  float* out = (float*)d_out;
  float* w   = (float*)d_ws;
  float* pt  = w;
  float* p1s = pt  + PSZ;
  float* p3s = p1s + PSZ;
  float* er  = p3s + PSZ;
  unsigned* ctr = (unsigned*)(er + ERSZ);

  hipMemsetAsync(ctr, 0, 2*sizeof(unsigned), stream);   // ws is 0xAA-poisoned
  ucb_all<<<NBLK, 256, 0, stream>>>(x, mean, variance,
                                    pt, p1s, p3s, er, ctr, out);
}

// Round 7
// 85.101 us; speedup vs baseline: 2.9482x; 2.9482x over previous
//
#include <hip/hip_runtime.h>

// UCBNorm, 3 kernels. No atomics, no memset, no coop launch, no grid barrier
// (round 6: in-kernel agent-scope barrier = 197us of L2 coherence thrash).
//
// Math (softmax(prior) over size-1 axis == 1 -> constant 1/sqrt(1+EPS)):
//   p_k = exp(qa x^2 + qb x + qc)  (expanded -0.5(x-m)^2/(softplus(v)+EPS))
//   den = EPS + sum_k p,  tau = p/den,  S[k,d] = EPS + sum_{b,t} tau
//   e = (sum_t tau x)/(T S),  var = (sum_t tau^3 x^2)/(T S^3)
//   out = (1/sqrt(1+EPS)) * rden * (x * sum_k p r_k - sum_k p e_k r_k)
//
// k1:  512 blocks (b, 16-d slice, T-half); 16d x 16tp threads, LDS tree over
//      tp -> partials [2][K][B][D] (768 KB total, was 6 MB in r5).
// fin: 128 blocks; per thread (k,b,d) 6 loads; cross-b S via LDS; er[B][K][2][D].
// k2:  1024 blocks (b, 8-t chunk) x 256 d; recompute p, factored epilogue.

namespace {
constexpr int K = 8, B = 16, T = 512, D = 256;
constexpr float EPS = 1e-3f;
constexpr int DSL = 16;              // d per slice in k1
constexpr int NSL = D / DSL;         // 16 slices
constexpr int TCH = 2;               // t-chunks in k1
constexpr int TLC = T / TCH;         // 256 t per chunk
constexpr int TP  = 16;              // t-parallel threads
constexpr int RT  = TLC / TP;        // 16 t-iters per thread
constexpr int KS  = 3 * K;           // 24
constexpr int PSZ = TCH * K * B * D; // 65536 floats per partial array
}

__global__ __launch_bounds__(256) void ucb_k1(
    const float* __restrict__ x, const float* __restrict__ mean,
    const float* __restrict__ variance,
    float* __restrict__ pt, float* __restrict__ p1s, float* __restrict__ p3s)
{
  __shared__ float red[TP][DSL][KS + 1];   // 25.6 KB, stride 25

  const int tid = threadIdx.x;
  const int dl  = tid & 15;
  const int tp  = tid >> 4;
  const int bi  = blockIdx.x;
  const int b   = bi >> 5;
  const int sl  = (bi >> 1) & 15;
  const int tch = bi & 1;
  const int dd  = sl*DSL + dl;

  float qa[K], qb[K], qc[K];
#pragma unroll
  for (int k = 0; k < K; ++k) {
    float mk = mean[k*D + dd];
    float sp = log1pf(__expf(variance[k*D + dd]));   // softplus
    float nh = -0.5f / (sp + EPS);
    qa[k] = nh; qb[k] = -2.0f*nh*mk; qc[k] = nh*mk*mk;
  }

  float ast[K], as1[K], as3[K];
#pragma unroll
  for (int k = 0; k < K; ++k) { ast[k]=0.f; as1[k]=0.f; as3[k]=0.f; }

  // t = tch*TLC + tp + TP*j
  const float* xp = x + ((size_t)b*T + (size_t)tch*TLC + tp)*D + dd;
#pragma unroll 4
  for (int j = 0; j < RT; ++j) {
    float xv = xp[(size_t)j*TP*D];
    float x2 = xv*xv;
    float p[K];
#pragma unroll
    for (int k = 0; k < K; ++k)
      p[k] = __expf(fmaf(qa[k], x2, fmaf(qb[k], xv, qc[k])));
    float den = EPS + ((p[0]+p[1])+(p[2]+p[3])) + ((p[4]+p[5])+(p[6]+p[7]));
    float rden = __builtin_amdgcn_rcpf(den);
#pragma unroll
    for (int k = 0; k < K; ++k) {
      float tau = p[k]*rden;
      float tx  = tau*xv;
      ast[k] += tau;
      as1[k] += tx;
      as3[k]  = fmaf(tx*tx, tau, as3[k]);   // tau^3 x^2
    }
  }

#pragma unroll
  for (int k = 0; k < K; ++k) {
    red[tp][dl][3*k+0] = ast[k];
    red[tp][dl][3*k+1] = as1[k];
    red[tp][dl][3*k+2] = as3[k];
  }
  __syncthreads();

#pragma unroll
  for (int i = 0; i < 2; ++i) {            // 384 items
    const int item = tid + i*256;
    if (item < DSL*KS) {
      const int dloc = item / KS;
      const int ks   = item % KS;
      float s = 0.f;
#pragma unroll
      for (int t2 = 0; t2 < TP; ++t2) s += red[t2][dloc][ks];
      const int k = ks / 3, stat = ks % 3;
      const size_t idx = ((size_t)((tch*K + k)*B + b))*D + sl*DSL + dloc;
      if      (stat == 0) pt [idx] = s;
      else if (stat == 1) p1s[idx] = s;
      else                p3s[idx] = s;
    }
  }
}

__global__ __launch_bounds__(256) void ucb_fin(
    const float* __restrict__ pt, const float* __restrict__ p1s,
    const float* __restrict__ p3s, float* __restrict__ er)  // [B][K][2][D]
{
  // 128 blocks: (k, 16-d group); 256 thr = 16 b x 16 d
  __shared__ float reds[B][17];

  const int k  = blockIdx.x >> 4;
  const int d0 = (blockIdx.x & 15) * 16;
  const int dl = threadIdx.x & 15;
  const int bb = threadIdx.x >> 4;
  const int d  = d0 + dl;

  const size_t i0 = ((size_t)(k*B + bb))*D + d;          // tch=0
  const size_t i1 = i0 + (size_t)K*B*D;                  // tch=1
  const float a0 = pt [i0] + pt [i1];
  const float a1 = p1s[i0] + p1s[i1];
  const float a3 = p3s[i0] + p3s[i1];

  reds[bb][dl] = a0;
  __syncthreads();
  if (threadIdx.x < 16) {
    float s = 0.f;
#pragma unroll
    for (int b2 = 0; b2 < B; ++b2) s += reds[b2][threadIdx.x];
    reds[0][threadIdx.x] = 1.0f / (s + EPS);             // rS
  }
  __syncthreads();

  const float rS = reds[0][dl];
  const float rT = 1.0f / T;
  const float e  = a1 * rT * rS;
  const float vv = a3 * rT * (rS*rS*rS);
  const float r  = rsqrtf(vv + EPS);
  er[((size_t)(bb*K + k)*2 + 0)*D + d] = e;
  er[((size_t)(bb*K + k)*2 + 1)*D + d] = r;
}

__global__ __launch_bounds__(256) void ucb_k2(
    const float* __restrict__ x, const float* __restrict__ mean,
    const float* __restrict__ variance, const float* __restrict__ er,
    float* __restrict__ out)
{
  const int d  = threadIdx.x;
  const int b  = blockIdx.x >> 6;
  const int tc = blockIdx.x & 63;          // 64 chunks x 8 t

  float qa[K], qb[K], qc[K], rr[K], erc[K];
#pragma unroll
  for (int k = 0; k < K; ++k) {
    float mk = mean[k*D + d];
    float sp = log1pf(__expf(variance[k*D + d]));
    float nh = -0.5f / (sp + EPS);
    qa[k] = nh; qb[k] = -2.0f*nh*mk; qc[k] = nh*mk*mk;
    float e = er[((size_t)(b*K + k)*2 + 0)*D + d];
    float r = er[((size_t)(b*K + k)*2 + 1)*D + d];
    rr[k] = r; erc[k] = e*r;
  }

  const float isp = 0.99950037f;           // 1/sqrt(1+EPS)
  const size_t base = ((size_t)b*T + (size_t)tc*8)*D + d;
#pragma unroll
  for (int t = 0; t < 8; ++t) {
    float xv = x[base + (size_t)t*D];
    float x2 = xv*xv;
    float p[K];
#pragma unroll
    for (int k = 0; k < K; ++k)
      p[k] = __expf(fmaf(qa[k], x2, fmaf(qb[k], xv, qc[k])));
    float den = EPS + ((p[0]+p[1])+(p[2]+p[3])) + ((p[4]+p[5])+(p[6]+p[7]));
    float rden = __builtin_amdgcn_rcpf(den);
    float acc1 = 0.f, acc2 = 0.f;
#pragma unroll
    for (int k = 0; k < K; ++k) {
      acc1 = fmaf(p[k], rr[k],  acc1);     // sum p*r
      acc2 = fmaf(p[k], erc[k], acc2);     // sum p*e*r
    }
    out[base + (size_t)t*D] = (xv*acc1 - acc2) * rden * isp;
  }
}

extern "C" void kernel_launch(void* const* d_in, const int* in_sizes, int n_in,
                              void* d_out, int out_size, void* d_ws, size_t ws_size,
                              hipStream_t stream) {
  const float* x        = (const float*)d_in[0];
  const float* mean     = (const float*)d_in[1];
  const float* variance = (const float*)d_in[2];
  // d_in[3] (prior): softmax over size-1 axis == 1 -> constant baked in.

  float* out = (float*)d_out;
  float* w   = (float*)d_ws;
  float* pt  = w;            // [TCH][K][B][D] = 65536 floats
  float* p1s = pt  + PSZ;
  float* p3s = p1s + PSZ;
  float* er  = p3s + PSZ;    // [B][K][2][D] = 65536 floats
  // every ws element is written before it is read -> no memset needed

  ucb_k1 <<<B*NSL*TCH, 256, 0, stream>>>(x, mean, variance, pt, p1s, p3s);
  ucb_fin<<<K*(D/16),  256, 0, stream>>>(pt, p1s, p3s, er);
  ucb_k2 <<<B*64,      256, 0, stream>>>(x, mean, variance, er, out);
}